// Round 6
// baseline (337.874 us; speedup 1.0000x reference)
//
#include <hip/hip_runtime.h>
#include <hip/hip_bf16.h>

// h = x(65536x512) @ W^T(512x256) + bias_lin ; GroupNorm(8 groups of 32)
// ; min over 256 channels -> m[b] ; out[c*B+b] = m[b] + bias[c]
//
// R6: wave-autonomous, zero-LDS, zero-barrier. Each wave owns a 16-row strip
// and computes ALL 256 channels: acc = 16 x floatx4 (64 VGPR). A-fragments
// loaded straight from global x (row-contiguous 32B/lane); B-fragments
// streamed from packed P (L1/L2-resident, block's 4 waves in phase).
// GroupNorm (groups = ct pairs at fixed l15) + row-min entirely in-wave via
// 16-lane butterflies. Params pre-packed {bl,wg,bg,bias} for float4 loads.
#define B_ROWS 65536
#define K_DIM  512
#define EPS    1e-5f

using short8  = __attribute__((ext_vector_type(8))) short;
using floatx4 = __attribute__((ext_vector_type(4))) float;

__device__ __forceinline__ unsigned short f2bf(float f) {
    unsigned u = __builtin_bit_cast(unsigned, f);
    u += 0x7FFFu + ((u >> 16) & 1u);     // RNE
    return (unsigned short)(u >> 16);
}

// Pack W (256x512 fp32) into bf16 MFMA B-fragment order:
// P[((ct*16 + kk)*64 + lane)*8 + j] = bf16(W[ct*16 + (lane&15)][kk*32 + (lane>>4)*8 + j])
__global__ __launch_bounds__(64) void pack_w(const float* __restrict__ W,
                                             unsigned short* __restrict__ P) {
    int b    = blockIdx.x;           // 0..255
    int nt   = b >> 4, kk = b & 15;
    int lane = threadIdx.x;
    int l15  = lane & 15, quad = lane >> 4;
    const float* src = W + (size_t)(nt * 16 + l15) * K_DIM + kk * 32 + quad * 8;
    short8 v;
#pragma unroll
    for (int j = 0; j < 8; ++j) v[j] = (short)f2bf(src[j]);
    *(short8*)(P + ((size_t)(nt * 16 + kk) * 64 + lane) * 8) = v;
}

// PRM[c] = {bias_lin[c], wgn[c], bgn[c], bias[c]}
__global__ __launch_bounds__(256) void pack_prm(
    const float* __restrict__ bl, const float* __restrict__ wg,
    const float* __restrict__ bg, const float* __restrict__ bias,
    float* __restrict__ PRM) {
    int c = threadIdx.x;
    float4 p;
    p.x = bl[c]; p.y = wg[c]; p.z = bg[c]; p.w = bias[c];
    *(float4*)(PRM + c * 4) = p;
}

__global__ __launch_bounds__(256, 3) void fused(
    const float* __restrict__ X, const unsigned short* __restrict__ P,
    const float* __restrict__ PRM, float* __restrict__ out)
{
    const int tid  = threadIdx.x;
    const int wave = tid >> 6, lane = tid & 63;
    const int l15  = lane & 15, quad = lane >> 4;
    const size_t row0 = ((size_t)blockIdx.x * 4 + wave) * 16;

    const float* xrow = X + (row0 + l15) * K_DIM;

    floatx4 acc[16];
#pragma unroll
    for (int ct = 0; ct < 16; ++ct) acc[ct] = (floatx4){0.f, 0.f, 0.f, 0.f};

    // ---- K loop: A from global (own row, contiguous), B from packed P ----
#pragma unroll
    for (int kk = 0; kk < 16; ++kk) {
        float4 f0 = *(const float4*)(xrow + kk * 32 + quad * 8);
        float4 f1 = *(const float4*)(xrow + kk * 32 + quad * 8 + 4);
        short8 a;
        a[0] = (short)f2bf(f0.x); a[1] = (short)f2bf(f0.y);
        a[2] = (short)f2bf(f0.z); a[3] = (short)f2bf(f0.w);
        a[4] = (short)f2bf(f1.x); a[5] = (short)f2bf(f1.y);
        a[6] = (short)f2bf(f1.z); a[7] = (short)f2bf(f1.w);
#pragma unroll
        for (int ct = 0; ct < 16; ++ct) {
            short8 b = *(const short8*)(P + (((size_t)ct * 16 + kk) * 64 + lane) * 8);
            acc[ct] = __builtin_amdgcn_mfma_f32_16x16x32_bf16(a, b, acc[ct], 0, 0, 0);
        }
    }

    // ---- per-channel params: col = ct*16 + l15 ----
    float4 prm[16];
#pragma unroll
    for (int ct = 0; ct < 16; ++ct)
        prm[ct] = *(const float4*)(PRM + (size_t)(ct * 16 + l15) * 4);

    // ---- GroupNorm + min, fully in-wave. Row r = quad*4 + reg (x row0). ----
    float rmin[4];
#pragma unroll
    for (int reg = 0; reg < 4; ++reg) {
        float gmin = 1e30f;
#pragma unroll
        for (int g = 0; g < 8; ++g) {           // group g = ct {2g, 2g+1}
            float va = acc[2 * g][reg]     + prm[2 * g].x;
            float vb = acc[2 * g + 1][reg] + prm[2 * g + 1].x;
            float s = va + vb, ss = va * va + vb * vb;
#pragma unroll
            for (int m = 1; m < 16; m <<= 1) {  // 16-lane butterfly (in-quad)
                s  += __shfl_xor(s, m);
                ss += __shfl_xor(ss, m);
            }
            float mean = s * (1.0f / 32.0f);
            float var  = ss * (1.0f / 32.0f) - mean * mean;
            float inv  = rsqrtf(var + EPS);
            float ga = (va - mean) * inv * prm[2 * g].y     + prm[2 * g].z;
            float gb = (vb - mean) * inv * prm[2 * g + 1].y + prm[2 * g + 1].z;
            gmin = fminf(gmin, fminf(ga, gb));
        }
#pragma unroll
        for (int m = 1; m < 16; m <<= 1) gmin = fminf(gmin, __shfl_xor(gmin, m));
        rmin[reg] = gmin;                       // row-min, replicated over l15
    }

    // ---- store: out[(ct*16+l15)*B + row0 + quad*4 ..+3] = rmin[..] + bias_c
    // per instr: 16 cols x 64B contiguous (4 quads x float4) -> line-coalesced
#pragma unroll
    for (int ct = 0; ct < 16; ++ct) {
        float bc = prm[ct].w;
        float4 o;
        o.x = rmin[0] + bc; o.y = rmin[1] + bc;
        o.z = rmin[2] + bc; o.w = rmin[3] + bc;
        *(float4*)(out + (size_t)(ct * 16 + l15) * B_ROWS + row0 + quad * 4) = o;
    }
}

extern "C" void kernel_launch(void* const* d_in, const int* in_sizes, int n_in,
                              void* d_out, int out_size, void* d_ws, size_t ws_size,
                              hipStream_t stream) {
    const float* x    = (const float*)d_in[0];
    const float* w    = (const float*)d_in[1];
    const float* bl   = (const float*)d_in[2];
    const float* wg   = (const float*)d_in[3];
    const float* bg   = (const float*)d_in[4];
    const float* bias = (const float*)d_in[5];

    unsigned short* P   = (unsigned short*)d_ws;              // 256 KB packed bf16 W
    float*          PRM = (float*)((char*)d_ws + 256 * 1024); // 4 KB packed params
    float* out = (float*)d_out;

    hipLaunchKernelGGL(pack_w, dim3(256), dim3(64), 0, stream, w, P);
    hipLaunchKernelGGL(pack_prm, dim3(1), dim3(256), 0, stream, bl, wg, bg, bias, PRM);
    hipLaunchKernelGGL(fused, dim3(B_ROWS / 64), dim3(256), 0, stream, x, P, PRM, out);
}